// Round 3
// baseline (4004.738 us; speedup 1.0000x reference)
//
#include <hip/hip_runtime.h>
#include <hip/hip_bf16.h>
#include <math.h>

#define TP 257
#define ROWS 2056          // B * (SEQ+1)
#define ZDIM 1792          // RELU_DIM + LN_DIM + DIM
#define PREDIM 1536        // RELU_DIM + LN_DIM
#define QKVDIM 768
#define EMBD 256
#define NHEAD 8
#define HDIM 32

// ---------------------------------------------------------------------------
// u = concat([cls, emb[x] + sinusoidal_pe], axis=1)   (one row per block)
// ---------------------------------------------------------------------------
__global__ __launch_bounds__(256) void build_u_kernel(
    const int* __restrict__ x, const float* __restrict__ emb,
    const float* __restrict__ cls, float* __restrict__ u)
{
    int row = blockIdx.x;
    int e   = threadIdx.x;
    int b = row / TP, t = row % TP;
    float val;
    if (t == 0) {
        val = cls[e];
    } else {
        int tt = t - 1;
        int xi = x[b * 256 + tt];
        // ang = tt / 10000^(i2/256), i2 = e & ~1 ;  log(10000)/256 = 0.0359786726...
        float ang = (float)tt * expf(-(float)(e & ~1) * 0.035978672652993f);
        float pe  = (e & 1) ? cosf(ang) : sinf(ang);
        val = emb[(size_t)xi * EMBD + e] + pe;
    }
    u[(size_t)row * EMBD + e] = val;
}

// ---------------------------------------------------------------------------
// C(M x N) = X(M x K) @ W(N x K)^T + bias.   X = [X1 | X2] split at ksplit.
// 64x64 tile, BK=16, 256 threads, 4x4 microtile. fp32.
// ---------------------------------------------------------------------------
__global__ __launch_bounds__(256) void gemm_xwT_kernel(
    const float* __restrict__ X1, int lda1, int ksplit,
    const float* __restrict__ X2, int lda2,
    const float* __restrict__ W, const float* __restrict__ bias,
    float* __restrict__ C, int ldc, int M, int N, int K)
{
    __shared__ float Xs[16][68];   // [k][m], row stride 68 floats (16B-aligned rows)
    __shared__ float Ws[16][68];   // [k][n]
    int tid = threadIdx.x;
    int r0 = blockIdx.x * 64, c0 = blockIdx.y * 64;
    int ty = tid >> 4, tx = tid & 15;
    int lrow = tid >> 2;            // 0..63
    int lk4  = (tid & 3) << 2;      // 0,4,8,12
    float acc[4][4] = {};

    for (int k0 = 0; k0 < K; k0 += 16) {
        int k = k0 + lk4;
        float4 xv = make_float4(0.f, 0.f, 0.f, 0.f);
        int r = r0 + lrow;
        if (r < M) {
            if (k < ksplit) xv = *(const float4*)(X1 + (size_t)r * lda1 + k);
            else            xv = *(const float4*)(X2 + (size_t)r * lda2 + (k - ksplit));
        }
        int c = c0 + lrow;          // N is a multiple of 64: always in range
        float4 wv = *(const float4*)(W + (size_t)c * K + k);

        Xs[lk4 + 0][lrow] = xv.x; Xs[lk4 + 1][lrow] = xv.y;
        Xs[lk4 + 2][lrow] = xv.z; Xs[lk4 + 3][lrow] = xv.w;
        Ws[lk4 + 0][lrow] = wv.x; Ws[lk4 + 1][lrow] = wv.y;
        Ws[lk4 + 2][lrow] = wv.z; Ws[lk4 + 3][lrow] = wv.w;
        __syncthreads();

        #pragma unroll
        for (int kk = 0; kk < 16; ++kk) {
            float a[4], w[4];
            *(float4*)a = *(const float4*)&Xs[kk][ty << 2];
            *(float4*)w = *(const float4*)&Ws[kk][tx << 2];
            #pragma unroll
            for (int i = 0; i < 4; ++i)
                #pragma unroll
                for (int j = 0; j < 4; ++j)
                    acc[i][j] = fmaf(a[i], w[j], acc[i][j]);
        }
        __syncthreads();
    }

    #pragma unroll
    for (int i = 0; i < 4; ++i) {
        int r = r0 + (ty << 2) + i;
        if (r < M) {
            float* Cr = C + (size_t)r * ldc + c0 + (tx << 2);
            #pragma unroll
            for (int j = 0; j < 4; ++j) {
                float vb = bias ? bias[c0 + (tx << 2) + j] : 0.0f;
                Cr[j] = acc[i][j] + vb;
            }
        }
    }
}

// ---------------------------------------------------------------------------
// z[:, :1024] = relu(pre[:, :1024]); z[:, 1024:1536] = LN_256(pre[:, 1024:1536])
// one row per block, 256 threads
// ---------------------------------------------------------------------------
__global__ __launch_bounds__(256) void relu_ln_kernel(
    const float* __restrict__ pre, float* __restrict__ z)
{
    int row = blockIdx.x;
    int tid = threadIdx.x;
    const float* pr = pre + (size_t)row * PREDIM;
    float* zr = z + (size_t)row * ZDIM;

    #pragma unroll
    for (int i = 0; i < 4; ++i) {
        int c = tid + i * 256;
        float v = pr[c];
        zr[c] = v > 0.f ? v : 0.f;
    }

    __shared__ float warr[4][2];
    #pragma unroll
    for (int g = 0; g < 2; ++g) {
        float xv = pr[1024 + g * 256 + tid];
        float s = xv, s2 = xv * xv;
        #pragma unroll
        for (int off = 32; off; off >>= 1) {
            s  += __shfl_down(s, off);
            s2 += __shfl_down(s2, off);
        }
        int wave = tid >> 6, lane = tid & 63;
        if (lane == 0) { warr[wave][0] = s; warr[wave][1] = s2; }
        __syncthreads();
        float ts  = warr[0][0] + warr[1][0] + warr[2][0] + warr[3][0];
        float ts2 = warr[0][1] + warr[1][1] + warr[2][1] + warr[3][1];
        float mu  = ts * (1.0f / 256.0f);
        float var = ts2 * (1.0f / 256.0f) - mu * mu;
        float y = (xv - mu) * rsqrtf(var + 1e-5f);
        zr[1024 + g * 256 + tid] = y;
        __syncthreads();
    }
}

// ---------------------------------------------------------------------------
// attention for one (b,h) and a tile of 32 queries; 2 queries per wave,
// one half-wave each. K,Q staged in LDS (+pad), V from global (L2-resident).
// masked keys (pos > seq_len) are skipped: exp(-1e9 - max) == 0 in f32.
// ---------------------------------------------------------------------------
__global__ __launch_bounds__(256) void attn_kernel(
    const float* __restrict__ qkv, const int* __restrict__ seq_lens,
    float* __restrict__ z)
{
    __shared__ float Ks[TP][33];
    __shared__ float Qs[32][36];
    __shared__ float ps[4][2][264];

    int bh = blockIdx.x;
    int b = bh >> 3, h = bh & 7;
    int q0 = blockIdx.y * 32;
    int kend = seq_lens[b] + 1;
    if (kend > TP) kend = TP;
    int tid = threadIdx.x;

    for (int idx = tid; idx < kend * 32; idx += 256) {
        int kk = idx >> 5, d = idx & 31;
        Ks[kk][d] = qkv[((size_t)(b * TP + kk)) * QKVDIM + h * 96 + 32 + d];
    }
    for (int idx = tid; idx < 32 * 32; idx += 256) {
        int qq = idx >> 5, d = idx & 31;
        int qi = q0 + qq;
        Qs[qq][d] = (qi < TP) ? qkv[((size_t)(b * TP + qi)) * QKVDIM + h * 96 + d] : 0.0f;
    }
    __syncthreads();

    int wave = tid >> 6, lane = tid & 63;
    int half = lane >> 5, t = lane & 31;
    const float scale = 0.17677669529663687f;  // 1/sqrt(32)

    for (int sub = 0; sub < 4; ++sub) {
        int qloc = wave * 8 + sub * 2 + half;
        int qi = q0 + qloc;

        // scores for this query, keys t, t+32, ...
        float mx = -3.0e38f;
        for (int kk = t; kk < kend; kk += 32) {
            float s = 0.f;
            #pragma unroll
            for (int d = 0; d < 32; ++d) s += Qs[qloc][d] * Ks[kk][d];
            s *= scale;
            ps[wave][half][kk] = s;
            mx = fmaxf(mx, s);
        }
        #pragma unroll
        for (int off = 1; off < 32; off <<= 1) mx = fmaxf(mx, __shfl_xor(mx, off));

        float sum = 0.f;
        for (int kk = t; kk < kend; kk += 32) {
            float p = __expf(ps[wave][half][kk] - mx);
            ps[wave][half][kk] = p;
            sum += p;
        }
        #pragma unroll
        for (int off = 1; off < 32; off <<= 1) sum += __shfl_xor(sum, off);
        float inv = 1.0f / sum;
        __builtin_amdgcn_wave_barrier();

        // PV: lane t is output dim d
        const float* Vbase = qkv + ((size_t)(b * TP)) * QKVDIM + h * 96 + 64 + t;
        float o0 = 0.f, o1 = 0.f, o2 = 0.f, o3 = 0.f;
        int k = 0;
        for (; k + 4 <= kend; k += 4) {
            o0 += ps[wave][half][k + 0] * Vbase[(size_t)(k + 0) * QKVDIM];
            o1 += ps[wave][half][k + 1] * Vbase[(size_t)(k + 1) * QKVDIM];
            o2 += ps[wave][half][k + 2] * Vbase[(size_t)(k + 2) * QKVDIM];
            o3 += ps[wave][half][k + 3] * Vbase[(size_t)(k + 3) * QKVDIM];
        }
        for (; k < kend; ++k) o0 += ps[wave][half][k] * Vbase[(size_t)k * QKVDIM];
        float o = (o0 + o1) + (o2 + o3);
        if (qi < TP)
            z[((size_t)(b * TP + qi)) * ZDIM + PREDIM + h * HDIM + t] = o * inv;
        __builtin_amdgcn_wave_barrier();
    }
}

// ---------------------------------------------------------------------------
// out[b,c] = z[b,0,:] . W_cls[c,:] + b_cls[c]    (one wave per output)
// ---------------------------------------------------------------------------
__global__ __launch_bounds__(64) void cls_kernel(
    const float* __restrict__ z, const float* __restrict__ W,
    const float* __restrict__ bias, float* __restrict__ out)
{
    int o = blockIdx.x;
    int c = o & 15, b = o >> 4;
    int lane = threadIdx.x;
    const float* zr = z + (size_t)(b * TP) * ZDIM;
    const float* wr = W + (size_t)c * ZDIM;
    float s = 0.f;
    for (int j = lane; j < ZDIM; j += 64) s += zr[j] * wr[j];
    #pragma unroll
    for (int off = 32; off; off >>= 1) s += __shfl_down(s, off);
    if (lane == 0) out[b * 16 + c] = s + bias[c];
}

// ---------------------------------------------------------------------------
extern "C" void kernel_launch(void* const* d_in, const int* in_sizes, int n_in,
                              void* d_out, int out_size, void* d_ws, size_t ws_size,
                              hipStream_t stream) {
    const int*   x        = (const int*)d_in[0];
    const int*   seq_lens = (const int*)d_in[1];
    const float* emb      = (const float*)d_in[2];
    const float* cls      = (const float*)d_in[3];
    const float* A        = (const float*)d_in[4];
    const float* A_qkv    = (const float*)d_in[5];
    const float* b        = (const float*)d_in[6];
    const float* W_cls    = (const float*)d_in[7];
    const float* b_cls    = (const float*)d_in[8];
    float* out = (float*)d_out;

    float* ws  = (float*)d_ws;
    float* zA  = ws;
    float* zB  = zA + (size_t)ROWS * ZDIM;
    float* u   = zB + (size_t)ROWS * ZDIM;
    float* pre = u + (size_t)ROWS * EMBD;
    float* qkv = pre;   // overlapped: pre dead once relu_ln done; qkv dead once attn done

    hipMemsetAsync(zA, 0, (size_t)ROWS * ZDIM * sizeof(float), stream);
    build_u_kernel<<<ROWS, 256, 0, stream>>>(x, emb, cls, u);

    float* cur = zA;
    float* nxt = zB;
    for (int it = 0; it < 12; ++it) {
        // pre = [z | u] @ A^T + b
        gemm_xwT_kernel<<<dim3(33, 24), 256, 0, stream>>>(
            cur, ZDIM, ZDIM, u, EMBD, A, b, pre, PREDIM, ROWS, PREDIM, 2048);
        // z_new[:, :1536] = relu | layernorm
        relu_ln_kernel<<<ROWS, 256, 0, stream>>>(pre, nxt);
        // qkv = z_l @ A_qkv^T
        gemm_xwT_kernel<<<dim3(33, 12), 256, 0, stream>>>(
            nxt + 1024, ZDIM, 512, u, EMBD, A_qkv, nullptr, qkv, QKVDIM, ROWS, QKVDIM, 512);
        // z_new[:, 1536:] = attention
        attn_kernel<<<dim3(64, 9), 256, 0, stream>>>(qkv, seq_lens, nxt);
        float* tmp = cur; cur = nxt; nxt = tmp;
    }
    cls_kernel<<<128, 64, 0, stream>>>(cur, W_cls, b_cls, out);
}

// Round 6
// 1788.129 us; speedup vs baseline: 2.2396x; 2.2396x over previous
//
#include <hip/hip_runtime.h>
#include <hip/hip_bf16.h>
#include <math.h>

#define TP 257
#define ROWS 2056          // B * (SEQ+1)
#define XDIM 2048          // bf16 state row: [relu 1024 | ln 512 | attn 256 | u 256]
#define ZDIM 1792          // RELU_DIM + LN_DIM + DIM (classifier width)
#define PREDIM 1536
#define QKVDIM 768
#define EMBD 256

using f32x4  = __attribute__((ext_vector_type(4))) float;
using bf16x8 = __attribute__((ext_vector_type(8))) short;

__device__ __forceinline__ ushort f2bf(float f) {
    uint32_t u = __float_as_uint(f);
    return (ushort)((u + 0x7fffu + ((u >> 16) & 1u)) >> 16);   // RNE
}
__device__ __forceinline__ float bf2f(ushort u) {
    return __uint_as_float(((uint32_t)u) << 16);
}

#define GLD16(g, l) __builtin_amdgcn_global_load_lds( \
    (const __attribute__((address_space(1))) void*)(g), \
    (__attribute__((address_space(3))) void*)(l), 16, 0, 0)

// ---------------------------------------------------------------------------
// fp32 -> bf16 weight conversion (once per call)
// ---------------------------------------------------------------------------
__global__ __launch_bounds__(256) void f2bf_kernel(
    const float* __restrict__ in, ushort* __restrict__ out, int n)
{
    int i = blockIdx.x * 256 + threadIdx.x;
    if (i < n) out[i] = f2bf(in[i]);
}

// ---------------------------------------------------------------------------
// u-columns (1792..2047) of BOTH state buffers
// ---------------------------------------------------------------------------
__global__ __launch_bounds__(256) void build_u_kernel(
    const int* __restrict__ x, const float* __restrict__ emb,
    const float* __restrict__ cls, ushort* __restrict__ xbA, ushort* __restrict__ xbB)
{
    int row = blockIdx.x;
    int e   = threadIdx.x;
    int b = row / TP, t = row % TP;
    float val;
    if (t == 0) {
        val = cls[e];
    } else {
        int tt = t - 1;
        int xi = x[b * 256 + tt];
        float ang = (float)tt * expf(-(float)(e & ~1) * 0.035978672652993f);
        float pe  = (e & 1) ? cosf(ang) : sinf(ang);
        val = emb[(size_t)xi * EMBD + e] + pe;
    }
    ushort bv = f2bf(val);
    xbA[(size_t)row * XDIM + 1792 + e] = bv;
    xbB[(size_t)row * XDIM + 1792 + e] = bv;
}

// ---------------------------------------------------------------------------
// C(MxN) = X(MxK bf16) @ W(NxK bf16)^T + bias  (fp32 out)
// m97 structure: 128x128 tile, 4 waves (2x2), 4x4 16x16x32 frags, BK=32,
// global_load_lds width=16, linear LDS [128][32].
// One MFMA consumes full K=32: frag k-offset = (lane>>4)*8, one ds_read_b128
// per fragment -> 8 ds_read_b128 + 16 MFMA per K-step (m97 histogram).
// ---------------------------------------------------------------------------
__global__ __launch_bounds__(256) void gemm_bf16_kernel(
    const ushort* __restrict__ X, int ldx,
    const ushort* __restrict__ W,          // [N][K]
    const float* __restrict__ bias,
    float* __restrict__ C, int ldc, int M, int N, int K)
{
    __shared__ ushort As[128 * 32];
    __shared__ ushort Bs[128 * 32];
    int tid  = threadIdx.x;
    int lane = tid & 63, wv = tid >> 6;
    int wr = wv >> 1, wc = wv & 1;
    int r0 = blockIdx.x * 128, c0 = blockIdx.y * 128;

    f32x4 acc[4][4] = {};

    int srow = wv * 32 + (lane >> 2);      // staging row within tile (+ i*16)
    int skol = (lane & 3) * 8;             // staging k-offset (elements)
    int fk   = (lane >> 4) * 8;            // fragment k-offset (elements)

    for (int k0 = 0; k0 < K; k0 += 32) {
        #pragma unroll
        for (int i = 0; i < 2; ++i) {
            int rr = r0 + srow + i * 16;
            if (rr >= M) rr = M - 1;                    // clamp: harmless dup rows
            const ushort* ga = X + (size_t)rr * ldx + k0 + skol;
            GLD16(ga, &As[(wv * 32 + i * 16) * 32]);
            const ushort* gb = W + (size_t)(c0 + srow + i * 16) * K + k0 + skol;
            GLD16(gb, &Bs[(wv * 32 + i * 16) * 32]);
        }
        __syncthreads();

        bf16x8 a[4], b[4];
        #pragma unroll
        for (int m = 0; m < 4; ++m)
            a[m] = *(const bf16x8*)&As[(wr * 64 + m * 16 + (lane & 15)) * 32 + fk];
        #pragma unroll
        for (int n = 0; n < 4; ++n)
            b[n] = *(const bf16x8*)&Bs[(wc * 64 + n * 16 + (lane & 15)) * 32 + fk];
        #pragma unroll
        for (int m = 0; m < 4; ++m)
            #pragma unroll
            for (int n = 0; n < 4; ++n)
                acc[m][n] = __builtin_amdgcn_mfma_f32_16x16x32_bf16(a[m], b[n], acc[m][n], 0, 0, 0);
        __syncthreads();
    }

    // epilogue: D col = lane&15, row = (lane>>4)*4 + j   [m89/m91-verified]
    int crow = (lane >> 4) * 4;
    int ccol = lane & 15;
    #pragma unroll
    for (int m = 0; m < 4; ++m) {
        #pragma unroll
        for (int j = 0; j < 4; ++j) {
            int r = r0 + wr * 64 + m * 16 + crow + j;
            if (r < M) {
                float* Cr = C + (size_t)r * ldc + c0 + wc * 64;
                #pragma unroll
                for (int n = 0; n < 4; ++n) {
                    int cc = n * 16 + ccol;
                    float vb = bias ? bias[c0 + wc * 64 + cc] : 0.0f;
                    Cr[cc] = acc[m][n][j] + vb;
                }
            }
        }
    }
}

// ---------------------------------------------------------------------------
// z[:, :1024] = relu(pre[:, :1024]); z[:, 1024:1536] = LN_256 groups -> bf16
// ---------------------------------------------------------------------------
__global__ __launch_bounds__(256) void relu_ln_kernel(
    const float* __restrict__ pre, ushort* __restrict__ zb)
{
    int row = blockIdx.x;
    int tid = threadIdx.x;
    const float* pr = pre + (size_t)row * PREDIM;
    ushort* zr = zb + (size_t)row * XDIM;

    #pragma unroll
    for (int i = 0; i < 4; ++i) {
        int c = tid + i * 256;
        float v = pr[c];
        zr[c] = f2bf(v > 0.f ? v : 0.f);
    }

    __shared__ float warr[4][2];
    #pragma unroll
    for (int g = 0; g < 2; ++g) {
        float xv = pr[1024 + g * 256 + tid];
        float s = xv, s2 = xv * xv;
        #pragma unroll
        for (int off = 32; off; off >>= 1) {
            s  += __shfl_down(s, off);
            s2 += __shfl_down(s2, off);
        }
        int wave = tid >> 6, lane = tid & 63;
        if (lane == 0) { warr[wave][0] = s; warr[wave][1] = s2; }
        __syncthreads();
        float ts  = warr[0][0] + warr[1][0] + warr[2][0] + warr[3][0];
        float ts2 = warr[0][1] + warr[1][1] + warr[2][1] + warr[3][1];
        float mu  = ts * (1.0f / 256.0f);
        float var = ts2 * (1.0f / 256.0f) - mu * mu;
        float y = (xv - mu) * rsqrtf(var + 1e-5f);
        zr[1024 + g * 256 + tid] = f2bf(y);
        __syncthreads();
    }
}

// ---------------------------------------------------------------------------
// attention (fp32 math, bf16 output into state cols 1536..1791)
// ---------------------------------------------------------------------------
__global__ __launch_bounds__(256) void attn_kernel(
    const float* __restrict__ qkv, const int* __restrict__ seq_lens,
    ushort* __restrict__ zb)
{
    __shared__ float Ks[TP][33];
    __shared__ float Qs[32][36];
    __shared__ float ps[4][2][264];

    int bh = blockIdx.x;
    int b = bh >> 3, h = bh & 7;
    int q0 = blockIdx.y * 32;
    int kend = seq_lens[b] + 1;
    if (kend > TP) kend = TP;
    int tid = threadIdx.x;

    for (int idx = tid; idx < kend * 32; idx += 256) {
        int kk = idx >> 5, d = idx & 31;
        Ks[kk][d] = qkv[((size_t)(b * TP + kk)) * QKVDIM + h * 96 + 32 + d];
    }
    for (int idx = tid; idx < 32 * 32; idx += 256) {
        int qq = idx >> 5, d = idx & 31;
        int qi = q0 + qq;
        Qs[qq][d] = (qi < TP) ? qkv[((size_t)(b * TP + qi)) * QKVDIM + h * 96 + d] : 0.0f;
    }
    __syncthreads();

    int wave = tid >> 6, lane = tid & 63;
    int half = lane >> 5, t = lane & 31;
    const float scale = 0.17677669529663687f;  // 1/sqrt(32)

    for (int sub = 0; sub < 4; ++sub) {
        int qloc = wave * 8 + sub * 2 + half;
        int qi = q0 + qloc;

        float mx = -3.0e38f;
        for (int kk = t; kk < kend; kk += 32) {
            float s = 0.f;
            #pragma unroll
            for (int d = 0; d < 32; ++d) s += Qs[qloc][d] * Ks[kk][d];
            s *= scale;
            ps[wave][half][kk] = s;
            mx = fmaxf(mx, s);
        }
        #pragma unroll
        for (int off = 1; off < 32; off <<= 1) mx = fmaxf(mx, __shfl_xor(mx, off));

        float sum = 0.f;
        for (int kk = t; kk < kend; kk += 32) {
            float p = __expf(ps[wave][half][kk] - mx);
            ps[wave][half][kk] = p;
            sum += p;
        }
        #pragma unroll
        for (int off = 1; off < 32; off <<= 1) sum += __shfl_xor(sum, off);
        float inv = 1.0f / sum;
        __builtin_amdgcn_wave_barrier();

        const float* Vbase = qkv + ((size_t)(b * TP)) * QKVDIM + h * 96 + 64 + t;
        float o0 = 0.f, o1 = 0.f, o2 = 0.f, o3 = 0.f;
        int k = 0;
        for (; k + 4 <= kend; k += 4) {
            o0 += ps[wave][half][k + 0] * Vbase[(size_t)(k + 0) * QKVDIM];
            o1 += ps[wave][half][k + 1] * Vbase[(size_t)(k + 1) * QKVDIM];
            o2 += ps[wave][half][k + 2] * Vbase[(size_t)(k + 2) * QKVDIM];
            o3 += ps[wave][half][k + 3] * Vbase[(size_t)(k + 3) * QKVDIM];
        }
        for (; k < kend; ++k) o0 += ps[wave][half][k] * Vbase[(size_t)k * QKVDIM];
        float o = (o0 + o1) + (o2 + o3);
        if (qi < TP)
            zb[((size_t)(b * TP + qi)) * XDIM + PREDIM + h * 32 + t] = f2bf(o * inv);
        __builtin_amdgcn_wave_barrier();
    }
}

// ---------------------------------------------------------------------------
// out[b,c] = z[b,0,:1792] . W_cls[c,:] + b_cls[c]
// ---------------------------------------------------------------------------
__global__ __launch_bounds__(64) void cls_kernel(
    const ushort* __restrict__ zb, const float* __restrict__ W,
    const float* __restrict__ bias, float* __restrict__ out)
{
    int o = blockIdx.x;
    int c = o & 15, b = o >> 4;
    int lane = threadIdx.x;
    const ushort* zr = zb + (size_t)(b * TP) * XDIM;
    const float* wr = W + (size_t)c * ZDIM;
    float s = 0.f;
    for (int j = lane; j < ZDIM; j += 64) s += bf2f(zr[j]) * wr[j];
    #pragma unroll
    for (int off = 32; off; off >>= 1) s += __shfl_down(s, off);
    if (lane == 0) out[b * 16 + c] = s + bias[c];
}

// ---------------------------------------------------------------------------
extern "C" void kernel_launch(void* const* d_in, const int* in_sizes, int n_in,
                              void* d_out, int out_size, void* d_ws, size_t ws_size,
                              hipStream_t stream) {
    const int*   x        = (const int*)d_in[0];
    const int*   seq_lens = (const int*)d_in[1];
    const float* emb      = (const float*)d_in[2];
    const float* cls      = (const float*)d_in[3];
    const float* A        = (const float*)d_in[4];
    const float* A_qkv    = (const float*)d_in[5];
    const float* b        = (const float*)d_in[6];
    const float* W_cls    = (const float*)d_in[7];
    const float* b_cls    = (const float*)d_in[8];
    float* out = (float*)d_out;

    ushort* XbA = (ushort*)d_ws;
    ushort* XbB = XbA + (size_t)ROWS * XDIM;
    ushort* Ab  = XbB + (size_t)ROWS * XDIM;
    ushort* Aqb = Ab + (size_t)PREDIM * 2048;
    float*  pre = (float*)(Aqb + (size_t)QKVDIM * 512);
    float*  qkv = pre;   // overlapped lifetimes (pre dead after relu_ln)

    hipMemsetAsync(XbA, 0, (size_t)ROWS * XDIM * sizeof(ushort), stream);
    f2bf_kernel<<<(PREDIM * 2048 + 255) / 256, 256, 0, stream>>>(A, Ab, PREDIM * 2048);
    f2bf_kernel<<<(QKVDIM * 512 + 255) / 256, 256, 0, stream>>>(A_qkv, Aqb, QKVDIM * 512);
    build_u_kernel<<<ROWS, 256, 0, stream>>>(x, emb, cls, XbA, XbB);

    ushort* cur = XbA;
    ushort* nxt = XbB;
    for (int it = 0; it < 12; ++it) {
        // pre = [z | u] @ A^T + b      (X buffer holds z and u contiguously)
        gemm_bf16_kernel<<<dim3(17, 12), 256, 0, stream>>>(
            cur, XDIM, Ab, b, pre, PREDIM, ROWS, PREDIM, 2048);
        relu_ln_kernel<<<ROWS, 256, 0, stream>>>(pre, nxt);
        // qkv = z_l @ A_qkv^T          (z_l = cols 1024..1535 of nxt)
        gemm_bf16_kernel<<<dim3(17, 6), 256, 0, stream>>>(
            nxt + 1024, XDIM, Aqb, nullptr, qkv, QKVDIM, ROWS, QKVDIM, 512);
        attn_kernel<<<dim3(64, 9), 256, 0, stream>>>(qkv, seq_lens, nxt);
        ushort* tmp = cur; cur = nxt; nxt = tmp;
    }
    cls_kernel<<<128, 64, 0, stream>>>(cur, W_cls, b_cls, out);
}

// Round 9
// 1186.684 us; speedup vs baseline: 3.3747x; 1.5068x over previous
//
#include <hip/hip_runtime.h>
#include <hip/hip_bf16.h>
#include <math.h>

#define TP 257
#define ROWS 2056          // B * (SEQ+1)
#define XDIM 2048          // bf16 state row: [relu 1024 | ln 512 | attn 256 | u 256]
#define ZDIM 1792          // RELU_DIM + LN_DIM + DIM (classifier width)
#define PREDIM 1536
#define QKVDIM 768
#define EMBD 256

using f32x4  = __attribute__((ext_vector_type(4))) float;
using bf16x8 = __attribute__((ext_vector_type(8))) short;

__device__ __forceinline__ ushort f2bf(float f) {
    uint32_t u = __float_as_uint(f);
    return (ushort)((u + 0x7fffu + ((u >> 16) & 1u)) >> 16);   // RNE
}
__device__ __forceinline__ float bf2f(ushort u) {
    return __uint_as_float(((uint32_t)u) << 16);
}

#define GLD16(g, l) __builtin_amdgcn_global_load_lds( \
    (const __attribute__((address_space(1))) void*)(g), \
    (__attribute__((address_space(3))) void*)(l), 16, 0, 0)

// ---------------------------------------------------------------------------
// fp32 -> bf16 weight conversion (once per call)
// ---------------------------------------------------------------------------
__global__ __launch_bounds__(256) void f2bf_kernel(
    const float* __restrict__ in, ushort* __restrict__ out, int n)
{
    int i = blockIdx.x * 256 + threadIdx.x;
    if (i < n) out[i] = f2bf(in[i]);
}

// ---------------------------------------------------------------------------
// u-columns (1792..2047) of BOTH state buffers
// ---------------------------------------------------------------------------
__global__ __launch_bounds__(256) void build_u_kernel(
    const int* __restrict__ x, const float* __restrict__ emb,
    const float* __restrict__ cls, ushort* __restrict__ xbA, ushort* __restrict__ xbB)
{
    int row = blockIdx.x;
    int e   = threadIdx.x;
    int b = row / TP, t = row % TP;
    float val;
    if (t == 0) {
        val = cls[e];
    } else {
        int tt = t - 1;
        int xi = x[b * 256 + tt];
        float ang = (float)tt * expf(-(float)(e & ~1) * 0.035978672652993f);
        float pe  = (e & 1) ? cosf(ang) : sinf(ang);
        val = emb[(size_t)xi * EMBD + e] + pe;
    }
    ushort bv = f2bf(val);
    xbA[(size_t)row * XDIM + 1792 + e] = bv;
    xbB[(size_t)row * XDIM + 1792 + e] = bv;
}

// ---------------------------------------------------------------------------
// C(MxN) = X(MxK bf16) @ W(NxK bf16)^T + bias. fp32 out (C) or bf16 out (Cb).
// m97 structure: 128x128 tile, 4 waves (2x2), 4x4 16x16x32 frags, BK=32.
// ---------------------------------------------------------------------------
__global__ __launch_bounds__(256) void gemm_bf16_kernel(
    const ushort* __restrict__ X, int ldx,
    const ushort* __restrict__ W,          // [N][K]
    const float* __restrict__ bias,
    float* __restrict__ C, ushort* __restrict__ Cb,
    int ldc, int M, int N, int K)
{
    __shared__ ushort As[128 * 32];
    __shared__ ushort Bs[128 * 32];
    int tid  = threadIdx.x;
    int lane = tid & 63, wv = tid >> 6;
    int wr = wv >> 1, wc = wv & 1;
    int r0 = blockIdx.x * 128, c0 = blockIdx.y * 128;

    f32x4 acc[4][4] = {};

    int srow = wv * 32 + (lane >> 2);
    int skol = (lane & 3) * 8;
    int fk   = (lane >> 4) * 8;

    for (int k0 = 0; k0 < K; k0 += 32) {
        #pragma unroll
        for (int i = 0; i < 2; ++i) {
            int rr = r0 + srow + i * 16;
            if (rr >= M) rr = M - 1;
            const ushort* ga = X + (size_t)rr * ldx + k0 + skol;
            GLD16(ga, &As[(wv * 32 + i * 16) * 32]);
            const ushort* gb = W + (size_t)(c0 + srow + i * 16) * K + k0 + skol;
            GLD16(gb, &Bs[(wv * 32 + i * 16) * 32]);
        }
        __syncthreads();

        bf16x8 a[4], b[4];
        #pragma unroll
        for (int m = 0; m < 4; ++m)
            a[m] = *(const bf16x8*)&As[(wr * 64 + m * 16 + (lane & 15)) * 32 + fk];
        #pragma unroll
        for (int n = 0; n < 4; ++n)
            b[n] = *(const bf16x8*)&Bs[(wc * 64 + n * 16 + (lane & 15)) * 32 + fk];
        #pragma unroll
        for (int m = 0; m < 4; ++m)
            #pragma unroll
            for (int n = 0; n < 4; ++n)
                acc[m][n] = __builtin_amdgcn_mfma_f32_16x16x32_bf16(a[m], b[n], acc[m][n], 0, 0, 0);
        __syncthreads();
    }

    int crow = (lane >> 4) * 4;
    int ccol = lane & 15;
    #pragma unroll
    for (int m = 0; m < 4; ++m) {
        #pragma unroll
        for (int j = 0; j < 4; ++j) {
            int r = r0 + wr * 64 + m * 16 + crow + j;
            if (r < M) {
                #pragma unroll
                for (int n = 0; n < 4; ++n) {
                    int cc = n * 16 + ccol;
                    float vb = bias ? bias[c0 + wc * 64 + cc] : 0.0f;
                    float v = acc[m][n][j] + vb;
                    if (Cb) Cb[(size_t)r * ldc + c0 + wc * 64 + cc] = f2bf(v);
                    else    C [(size_t)r * ldc + c0 + wc * 64 + cc] = v;
                }
            }
        }
    }
}

// ---------------------------------------------------------------------------
// z[:, :1024] = relu(pre[:, :1024]); z[:, 1024:1536] = LN_256 groups -> bf16
// ---------------------------------------------------------------------------
__global__ __launch_bounds__(256) void relu_ln_kernel(
    const float* __restrict__ pre, ushort* __restrict__ zb)
{
    int row = blockIdx.x;
    int tid = threadIdx.x;
    const float* pr = pre + (size_t)row * PREDIM;
    ushort* zr = zb + (size_t)row * XDIM;

    #pragma unroll
    for (int i = 0; i < 4; ++i) {
        int c = tid + i * 256;
        float v = pr[c];
        zr[c] = f2bf(v > 0.f ? v : 0.f);
    }

    __shared__ float warr[4][2];
    #pragma unroll
    for (int g = 0; g < 2; ++g) {
        float xv = pr[1024 + g * 256 + tid];
        float s = xv, s2 = xv * xv;
        #pragma unroll
        for (int off = 32; off; off >>= 1) {
            s  += __shfl_down(s, off);
            s2 += __shfl_down(s2, off);
        }
        int wave = tid >> 6, lane = tid & 63;
        if (lane == 0) { warr[wave][0] = s; warr[wave][1] = s2; }
        __syncthreads();
        float ts  = warr[0][0] + warr[1][0] + warr[2][0] + warr[3][0];
        float ts2 = warr[0][1] + warr[1][1] + warr[2][1] + warr[3][1];
        float mu  = ts * (1.0f / 256.0f);
        float var = ts2 * (1.0f / 256.0f) - mu * mu;
        float y = (xv - mu) * rsqrtf(var + 1e-5f);
        zr[1024 + g * 256 + tid] = f2bf(y);
        __syncthreads();
    }
}

// ---------------------------------------------------------------------------
// MFMA attention. Block = (b,h) x q-chunk(64). 4 waves, 16 queries each.
// K_lds [288][40] bf16, VT_lds [32][296] bf16, P chunk buffer per wave.
// S = Q@K^T: A=Q-rows, B=K-rows (convention validated by passing GEMM).
// C-layout: key = lane&15, q = (lane>>4)*4+j. Masked -> -1e30 before max/exp.
// PV: O = P@(VT)^T: A=P-rows (q x keys), B=VT-rows (d x keys).
// ---------------------------------------------------------------------------
__global__ __launch_bounds__(256) void attn_kernel(
    const ushort* __restrict__ qkvb, const int* __restrict__ seq_lens,
    ushort* __restrict__ zb)
{
    __shared__ ushort Kl[288 * 40];
    __shared__ ushort VTl[32 * 296];
    __shared__ ushort Pl[4][16 * 40];

    int bh = blockIdx.x;
    int b = bh >> 3, h = bh & 7;
    int kend = seq_lens[b] + 1; if (kend > TP) kend = TP;
    int tid = threadIdx.x;
    const size_t qbase = (size_t)(b * TP) * QKVDIM + h * 96;

    // zero pad regions (K rows >=257, VT cols >=257): must be finite
    for (int idx = tid; idx < 31 * 32; idx += 256) {
        int row = 257 + (idx >> 5), d = idx & 31;
        Kl[row * 40 + d] = 0;
    }
    for (int idx = tid; idx < 32 * 32; idx += 256) {
        int d = idx >> 5, col = 257 + (idx & 31);
        VTl[d * 296 + col] = 0;
    }
    // stage K (16B chunks, row-padded to 40 ushorts: 2-way banks only)
    for (int idx = tid; idx < 257 * 4; idx += 256) {
        int row = idx >> 2, seg = idx & 3;
        *(bf16x8*)&Kl[row * 40 + seg * 8] =
            *(const bf16x8*)&qkvb[qbase + (size_t)row * QKVDIM + 32 + seg * 8];
    }
    // stage V transposed
    for (int idx = tid; idx < 257 * 32; idx += 256) {
        int key = idx >> 5, d = idx & 31;
        VTl[d * 296 + key] = qkvb[qbase + (size_t)key * QKVDIM + 64 + d];
    }
    __syncthreads();

    int wave = tid >> 6, lane = tid & 63;
    int q0 = blockIdx.y * 64 + wave * 16;
    if (q0 > 256) return;                       // no later barriers
    int qcol = lane & 15, g = lane >> 4;
    int ktmax = (kend + 15) >> 4;
    const float scale = 0.17677669529663687f;   // 1/sqrt(32)

    int qg = q0 + qcol; if (qg > 256) qg = 256; // clamp: dup row, write-guarded
    bf16x8 aq = *(const bf16x8*)&qkvb[qbase + (size_t)qg * QKVDIM + g * 8];

    f32x4 s[17];
    const f32x4 zz = {};
    #pragma unroll
    for (int kt = 0; kt < 17; ++kt) {
        s[kt] = (f32x4)(-1e30f);
        if (kt < ktmax) {
            bf16x8 bk = *(const bf16x8*)&Kl[(kt * 16 + qcol) * 40 + g * 8];
            f32x4 r = __builtin_amdgcn_mfma_f32_16x16x32_bf16(aq, bk, zz, 0, 0, 0);
            bool kv = (kt * 16 + qcol) < kend;
            #pragma unroll
            for (int j = 0; j < 4; ++j)
                s[kt][j] = kv ? r[j] * scale : -1e30f;
        }
    }

    float m0[4], l0[4];
    #pragma unroll
    for (int j = 0; j < 4; ++j) m0[j] = -3.0e38f;
    #pragma unroll
    for (int kt = 0; kt < 17; ++kt)
        #pragma unroll
        for (int j = 0; j < 4; ++j) m0[j] = fmaxf(m0[j], s[kt][j]);
    #pragma unroll
    for (int j = 0; j < 4; ++j) {
        #pragma unroll
        for (int off = 1; off < 16; off <<= 1)
            m0[j] = fmaxf(m0[j], __shfl_xor(m0[j], off));
        l0[j] = 0.f;
    }
    #pragma unroll
    for (int kt = 0; kt < 17; ++kt)
        #pragma unroll
        for (int j = 0; j < 4; ++j) {
            float p = __expf(s[kt][j] - m0[j]);   // masked: exp(-1e30-m) = 0
            s[kt][j] = p;
            l0[j] += p;
        }
    #pragma unroll
    for (int j = 0; j < 4; ++j) {
        #pragma unroll
        for (int off = 1; off < 16; off <<= 1)
            l0[j] += __shfl_xor(l0[j], off);
        l0[j] = 1.0f / l0[j];
    }
    #pragma unroll
    for (int kt = 0; kt < 17; ++kt)
        #pragma unroll
        for (int j = 0; j < 4; ++j) s[kt][j] *= l0[j];

    // PV over 32-key chunks; P round-trips via per-wave LDS (same-wave lgkm)
    f32x4 o[2] = {};
    ushort* Pw = Pl[wave];
    #pragma unroll
    for (int c = 0; c < 9; ++c) {
        if (c * 32 < kend) {
            #pragma unroll
            for (int t = 0; t < 2; ++t)
                #pragma unroll
                for (int j = 0; j < 4; ++j)
                    Pw[(g * 4 + j) * 40 + t * 16 + qcol] = f2bf(s[2 * c + t][j]);
            bf16x8 pa = *(const bf16x8*)&Pw[qcol * 40 + g * 8];
            #pragma unroll
            for (int n = 0; n < 2; ++n) {
                bf16x8 vb = *(const bf16x8*)&VTl[(n * 16 + qcol) * 296 + c * 32 + g * 8];
                o[n] = __builtin_amdgcn_mfma_f32_16x16x32_bf16(pa, vb, o[n], 0, 0, 0);
            }
        }
    }

    #pragma unroll
    for (int n = 0; n < 2; ++n)
        #pragma unroll
        for (int j = 0; j < 4; ++j) {
            int q = q0 + g * 4 + j;
            if (q <= 256)
                zb[(size_t)(b * TP + q) * XDIM + PREDIM + h * 32 + n * 16 + qcol] =
                    f2bf(o[n][j]);
        }
}

// ---------------------------------------------------------------------------
// out[b,c] = z[b,0,:1792] . W_cls[c,:] + b_cls[c]
// ---------------------------------------------------------------------------
__global__ __launch_bounds__(64) void cls_kernel(
    const ushort* __restrict__ zb, const float* __restrict__ W,
    const float* __restrict__ bias, float* __restrict__ out)
{
    int o = blockIdx.x;
    int c = o & 15, b = o >> 4;
    int lane = threadIdx.x;
    const ushort* zr = zb + (size_t)(b * TP) * XDIM;
    const float* wr = W + (size_t)c * ZDIM;
    float s = 0.f;
    for (int j = lane; j < ZDIM; j += 64) s += bf2f(zr[j]) * wr[j];
    #pragma unroll
    for (int off = 32; off; off >>= 1) s += __shfl_down(s, off);
    if (lane == 0) out[b * 16 + c] = s + bias[c];
}

// ---------------------------------------------------------------------------
extern "C" void kernel_launch(void* const* d_in, const int* in_sizes, int n_in,
                              void* d_out, int out_size, void* d_ws, size_t ws_size,
                              hipStream_t stream) {
    const int*   x        = (const int*)d_in[0];
    const int*   seq_lens = (const int*)d_in[1];
    const float* emb      = (const float*)d_in[2];
    const float* cls      = (const float*)d_in[3];
    const float* A        = (const float*)d_in[4];
    const float* A_qkv    = (const float*)d_in[5];
    const float* b        = (const float*)d_in[6];
    const float* W_cls    = (const float*)d_in[7];
    const float* b_cls    = (const float*)d_in[8];
    float* out = (float*)d_out;

    ushort* XbA  = (ushort*)d_ws;
    ushort* XbB  = XbA + (size_t)ROWS * XDIM;
    ushort* Ab   = XbB + (size_t)ROWS * XDIM;
    ushort* Aqb  = Ab + (size_t)PREDIM * 2048;
    float*  pre  = (float*)(Aqb + (size_t)QKVDIM * 512);
    ushort* qkvb = (ushort*)pre;   // overlapped: pre dead after relu_ln

    hipMemsetAsync(XbA, 0, (size_t)ROWS * XDIM * sizeof(ushort), stream);
    f2bf_kernel<<<(PREDIM * 2048 + 255) / 256, 256, 0, stream>>>(A, Ab, PREDIM * 2048);
    f2bf_kernel<<<(QKVDIM * 512 + 255) / 256, 256, 0, stream>>>(A_qkv, Aqb, QKVDIM * 512);
    build_u_kernel<<<ROWS, 256, 0, stream>>>(x, emb, cls, XbA, XbB);

    ushort* cur = XbA;
    ushort* nxt = XbB;
    for (int it = 0; it < 12; ++it) {
        gemm_bf16_kernel<<<dim3(17, 12), 256, 0, stream>>>(
            cur, XDIM, Ab, b, pre, nullptr, PREDIM, ROWS, PREDIM, 2048);
        relu_ln_kernel<<<ROWS, 256, 0, stream>>>(pre, nxt);
        gemm_bf16_kernel<<<dim3(17, 6), 256, 0, stream>>>(
            nxt + 1024, XDIM, Aqb, nullptr, nullptr, qkvb, QKVDIM, ROWS, QKVDIM, 512);
        attn_kernel<<<dim3(64, 5), 256, 0, stream>>>(qkvb, seq_lens, nxt);
        ushort* tmp = cur; cur = nxt; nxt = tmp;
    }
    cls_kernel<<<128, 64, 0, stream>>>(cur, W_cls, b_cls, out);
}

// Round 11
// 1013.501 us; speedup vs baseline: 3.9514x; 1.1709x over previous
//
#include <hip/hip_runtime.h>
#include <hip/hip_bf16.h>
#include <math.h>

#define TP 257
#define ROWS 2056          // B * (SEQ+1)
#define XDIM 2048          // bf16 state row: [relu 1024 | ln 512 | attn 256 | u 256]
#define ZDIM 1792          // RELU_DIM + LN_DIM + DIM (classifier width)
#define PREDIM 1536
#define QKVDIM 768
#define EMBD 256

using f32x4  = __attribute__((ext_vector_type(4))) float;
using bf16x8 = __attribute__((ext_vector_type(8))) short;

__device__ __forceinline__ ushort f2bf(float f) {
    uint32_t u = __float_as_uint(f);
    return (ushort)((u + 0x7fffu + ((u >> 16) & 1u)) >> 16);   // RNE
}
__device__ __forceinline__ float bf2f(ushort u) {
    return __uint_as_float(((uint32_t)u) << 16);
}

#define GLD16(g, l) __builtin_amdgcn_global_load_lds( \
    (const __attribute__((address_space(1))) void*)(g), \
    (__attribute__((address_space(3))) void*)(l), 16, 0, 0)

// ---------------------------------------------------------------------------
// fp32 -> bf16 weight conversion (once per call)
// ---------------------------------------------------------------------------
__global__ __launch_bounds__(256) void f2bf_kernel(
    const float* __restrict__ in, ushort* __restrict__ out, int n)
{
    int i = blockIdx.x * 256 + threadIdx.x;
    if (i < n) out[i] = f2bf(in[i]);
}

// ---------------------------------------------------------------------------
// u-columns (1792..2047) of BOTH state buffers
// ---------------------------------------------------------------------------
__global__ __launch_bounds__(256) void build_u_kernel(
    const int* __restrict__ x, const float* __restrict__ emb,
    const float* __restrict__ cls, ushort* __restrict__ xbA, ushort* __restrict__ xbB)
{
    int row = blockIdx.x;
    int e   = threadIdx.x;
    int b = row / TP, t = row % TP;
    float val;
    if (t == 0) {
        val = cls[e];
    } else {
        int tt = t - 1;
        int xi = x[b * 256 + tt];
        float ang = (float)tt * expf(-(float)(e & ~1) * 0.035978672652993f);
        float pe  = (e & 1) ? cosf(ang) : sinf(ang);
        val = emb[(size_t)xi * EMBD + e] + pe;
    }
    ushort bv = f2bf(val);
    xbA[(size_t)row * XDIM + 1792 + e] = bv;
    xbB[(size_t)row * XDIM + 1792 + e] = bv;
}

// ---------------------------------------------------------------------------
// C(MxN) = X(MxK bf16) @ W(NxK bf16)^T (+ bias). fp32 out (C) or bf16 (Cb).
// m97 structure: 128x128 tile, 4 waves (2x2), 4x4 16x16x32 frags, BK=32.
// Split-K: blockIdx.z processes K-range [z*Ksplit, (z+1)*Ksplit); fp32 partial
// sums land at C + z*splitStride. Bias only from z==0. (Latency fix: grid
// 204->408 blocks; 204 blocks on 256 CUs left CUs idle & loads unhidden.)
// ---------------------------------------------------------------------------
__global__ __launch_bounds__(256) void gemm_bf16_kernel(
    const ushort* __restrict__ X, int ldx,
    const ushort* __restrict__ W,          // [N][Ktotal]
    const float* __restrict__ bias,
    float* __restrict__ C, ushort* __restrict__ Cb,
    int ldc, int M, int N, int Ksplit, int Ktotal, size_t splitStride)
{
    __shared__ ushort As[128 * 32];
    __shared__ ushort Bs[128 * 32];
    int tid  = threadIdx.x;
    int lane = tid & 63, wv = tid >> 6;
    int wr = wv >> 1, wc = wv & 1;
    int r0 = blockIdx.x * 128, c0 = blockIdx.y * 128;
    int kbeg = blockIdx.z * Ksplit;
    int kfin = kbeg + Ksplit;

    f32x4 acc[4][4] = {};

    int srow = wv * 32 + (lane >> 2);
    int skol = (lane & 3) * 8;
    int fk   = (lane >> 4) * 8;

    for (int k0 = kbeg; k0 < kfin; k0 += 32) {
        #pragma unroll
        for (int i = 0; i < 2; ++i) {
            int rr = r0 + srow + i * 16;
            if (rr >= M) rr = M - 1;
            const ushort* ga = X + (size_t)rr * ldx + k0 + skol;
            GLD16(ga, &As[(wv * 32 + i * 16) * 32]);
            const ushort* gb = W + (size_t)(c0 + srow + i * 16) * Ktotal + k0 + skol;
            GLD16(gb, &Bs[(wv * 32 + i * 16) * 32]);
        }
        __syncthreads();

        bf16x8 a[4], b[4];
        #pragma unroll
        for (int m = 0; m < 4; ++m)
            a[m] = *(const bf16x8*)&As[(wr * 64 + m * 16 + (lane & 15)) * 32 + fk];
        #pragma unroll
        for (int n = 0; n < 4; ++n)
            b[n] = *(const bf16x8*)&Bs[(wc * 64 + n * 16 + (lane & 15)) * 32 + fk];
        #pragma unroll
        for (int m = 0; m < 4; ++m)
            #pragma unroll
            for (int n = 0; n < 4; ++n)
                acc[m][n] = __builtin_amdgcn_mfma_f32_16x16x32_bf16(a[m], b[n], acc[m][n], 0, 0, 0);
        __syncthreads();
    }

    // epilogue: D col = lane&15, row = (lane>>4)*4 + j   [m89/m91-verified]
    int crow = (lane >> 4) * 4;
    int ccol = lane & 15;
    float* Cz = C ? C + (size_t)blockIdx.z * splitStride : nullptr;
    bool addb = (bias != nullptr) && (blockIdx.z == 0);
    #pragma unroll
    for (int m = 0; m < 4; ++m) {
        #pragma unroll
        for (int j = 0; j < 4; ++j) {
            int r = r0 + wr * 64 + m * 16 + crow + j;
            if (r < M) {
                #pragma unroll
                for (int n = 0; n < 4; ++n) {
                    int cc = n * 16 + ccol;
                    float vb = addb ? bias[c0 + wc * 64 + cc] : 0.0f;
                    float v = acc[m][n][j] + vb;
                    if (Cb) Cb[(size_t)r * ldc + c0 + wc * 64 + cc] = f2bf(v);
                    else    Cz[(size_t)r * ldc + c0 + wc * 64 + cc] = v;
                }
            }
        }
    }
}

// ---------------------------------------------------------------------------
// z[:, :1024] = relu(pre0+pre1); z[:, 1024:1536] = LN_256(pre0+pre1) -> bf16
// pre1 may be null (no split-K fallback). float4 / ushort4 vectorized.
// ---------------------------------------------------------------------------
__global__ __launch_bounds__(256) void relu_ln_kernel(
    const float* __restrict__ pre0, const float* __restrict__ pre1,
    ushort* __restrict__ zb)
{
    int row = blockIdx.x;
    int tid = threadIdx.x;
    const float* p0 = pre0 + (size_t)row * PREDIM;
    const float* p1 = pre1 ? pre1 + (size_t)row * PREDIM : nullptr;
    ushort* zr = zb + (size_t)row * XDIM;

    // relu: cols 4*tid .. 4*tid+3   (256 threads x 4 = 1024)
    float4 v = *(const float4*)(p0 + 4 * tid);
    if (p1) {
        float4 w = *(const float4*)(p1 + 4 * tid);
        v.x += w.x; v.y += w.y; v.z += w.z; v.w += w.w;
    }
    ushort4 o;
    o.x = f2bf(v.x > 0.f ? v.x : 0.f);
    o.y = f2bf(v.y > 0.f ? v.y : 0.f);
    o.z = f2bf(v.z > 0.f ? v.z : 0.f);
    o.w = f2bf(v.w > 0.f ? v.w : 0.f);
    *(ushort4*)(zr + 4 * tid) = o;

    __shared__ float warr[4][2];
    #pragma unroll
    for (int g = 0; g < 2; ++g) {
        int c = 1024 + g * 256 + tid;
        float xv = p0[c] + (p1 ? p1[c] : 0.f);
        float s = xv, s2 = xv * xv;
        #pragma unroll
        for (int off = 32; off; off >>= 1) {
            s  += __shfl_down(s, off);
            s2 += __shfl_down(s2, off);
        }
        int wave = tid >> 6, lane = tid & 63;
        if (lane == 0) { warr[wave][0] = s; warr[wave][1] = s2; }
        __syncthreads();
        float ts  = warr[0][0] + warr[1][0] + warr[2][0] + warr[3][0];
        float ts2 = warr[0][1] + warr[1][1] + warr[2][1] + warr[3][1];
        float mu  = ts * (1.0f / 256.0f);
        float var = ts2 * (1.0f / 256.0f) - mu * mu;
        float y = (xv - mu) * rsqrtf(var + 1e-5f);
        zr[c] = f2bf(y);
        __syncthreads();
    }
}

// ---------------------------------------------------------------------------
// MFMA attention. Block = (b,h) x q-chunk(64). 4 waves, 16 queries each.
// ---------------------------------------------------------------------------
__global__ __launch_bounds__(256) void attn_kernel(
    const ushort* __restrict__ qkvb, const int* __restrict__ seq_lens,
    ushort* __restrict__ zb)
{
    __shared__ ushort Kl[288 * 40];
    __shared__ ushort VTl[32 * 296];
    __shared__ ushort Pl[4][16 * 40];

    int bh = blockIdx.x;
    int b = bh >> 3, h = bh & 7;
    int kend = seq_lens[b] + 1; if (kend > TP) kend = TP;
    int tid = threadIdx.x;
    const size_t qbase = (size_t)(b * TP) * QKVDIM + h * 96;

    for (int idx = tid; idx < 31 * 32; idx += 256) {
        int row = 257 + (idx >> 5), d = idx & 31;
        Kl[row * 40 + d] = 0;
    }
    for (int idx = tid; idx < 32 * 32; idx += 256) {
        int d = idx >> 5, col = 257 + (idx & 31);
        VTl[d * 296 + col] = 0;
    }
    for (int idx = tid; idx < 257 * 4; idx += 256) {
        int row = idx >> 2, seg = idx & 3;
        *(bf16x8*)&Kl[row * 40 + seg * 8] =
            *(const bf16x8*)&qkvb[qbase + (size_t)row * QKVDIM + 32 + seg * 8];
    }
    for (int idx = tid; idx < 257 * 32; idx += 256) {
        int key = idx >> 5, d = idx & 31;
        VTl[d * 296 + key] = qkvb[qbase + (size_t)key * QKVDIM + 64 + d];
    }
    __syncthreads();

    int wave = tid >> 6, lane = tid & 63;
    int q0 = blockIdx.y * 64 + wave * 16;
    if (q0 > 256) return;
    int qcol = lane & 15, g = lane >> 4;
    int ktmax = (kend + 15) >> 4;
    const float scale = 0.17677669529663687f;

    int qg = q0 + qcol; if (qg > 256) qg = 256;
    bf16x8 aq = *(const bf16x8*)&qkvb[qbase + (size_t)qg * QKVDIM + g * 8];

    f32x4 s[17];
    const f32x4 zz = {};
    #pragma unroll
    for (int kt = 0; kt < 17; ++kt) {
        s[kt] = (f32x4)(-1e30f);
        if (kt < ktmax) {
            bf16x8 bk = *(const bf16x8*)&Kl[(kt * 16 + qcol) * 40 + g * 8];
            f32x4 r = __builtin_amdgcn_mfma_f32_16x16x32_bf16(aq, bk, zz, 0, 0, 0);
            bool kv = (kt * 16 + qcol) < kend;
            #pragma unroll
            for (int j = 0; j < 4; ++j)
                s[kt][j] = kv ? r[j] * scale : -1e30f;
        }
    }

    float m0[4], l0[4];
    #pragma unroll
    for (int j = 0; j < 4; ++j) m0[j] = -3.0e38f;
    #pragma unroll
    for (int kt = 0; kt < 17; ++kt)
        #pragma unroll
        for (int j = 0; j < 4; ++j) m0[j] = fmaxf(m0[j], s[kt][j]);
    #pragma unroll
    for (int j = 0; j < 4; ++j) {
        #pragma unroll
        for (int off = 1; off < 16; off <<= 1)
            m0[j] = fmaxf(m0[j], __shfl_xor(m0[j], off));
        l0[j] = 0.f;
    }
    #pragma unroll
    for (int kt = 0; kt < 17; ++kt)
        #pragma unroll
        for (int j = 0; j < 4; ++j) {
            float p = __expf(s[kt][j] - m0[j]);
            s[kt][j] = p;
            l0[j] += p;
        }
    #pragma unroll
    for (int j = 0; j < 4; ++j) {
        #pragma unroll
        for (int off = 1; off < 16; off <<= 1)
            l0[j] += __shfl_xor(l0[j], off);
        l0[j] = 1.0f / l0[j];
    }
    #pragma unroll
    for (int kt = 0; kt < 17; ++kt)
        #pragma unroll
        for (int j = 0; j < 4; ++j) s[kt][j] *= l0[j];

    f32x4 o[2] = {};
    ushort* Pw = Pl[wave];
    #pragma unroll
    for (int c = 0; c < 9; ++c) {
        if (c * 32 < kend) {
            #pragma unroll
            for (int t = 0; t < 2; ++t)
                #pragma unroll
                for (int j = 0; j < 4; ++j)
                    Pw[(g * 4 + j) * 40 + t * 16 + qcol] = f2bf(s[2 * c + t][j]);
            bf16x8 pa = *(const bf16x8*)&Pw[qcol * 40 + g * 8];
            #pragma unroll
            for (int n = 0; n < 2; ++n) {
                bf16x8 vb = *(const bf16x8*)&VTl[(n * 16 + qcol) * 296 + c * 32 + g * 8];
                o[n] = __builtin_amdgcn_mfma_f32_16x16x32_bf16(pa, vb, o[n], 0, 0, 0);
            }
        }
    }

    #pragma unroll
    for (int n = 0; n < 2; ++n)
        #pragma unroll
        for (int j = 0; j < 4; ++j) {
            int q = q0 + g * 4 + j;
            if (q <= 256)
                zb[(size_t)(b * TP + q) * XDIM + PREDIM + h * 32 + n * 16 + qcol] =
                    f2bf(o[n][j]);
        }
}

// ---------------------------------------------------------------------------
// out[b,c] = z[b,0,:1792] . W_cls[c,:] + b_cls[c]
// ---------------------------------------------------------------------------
__global__ __launch_bounds__(64) void cls_kernel(
    const ushort* __restrict__ zb, const float* __restrict__ W,
    const float* __restrict__ bias, float* __restrict__ out)
{
    int o = blockIdx.x;
    int c = o & 15, b = o >> 4;
    int lane = threadIdx.x;
    const ushort* zr = zb + (size_t)(b * TP) * XDIM;
    const float* wr = W + (size_t)c * ZDIM;
    float s = 0.f;
    for (int j = lane; j < ZDIM; j += 64) s += bf2f(zr[j]) * wr[j];
    #pragma unroll
    for (int off = 32; off; off >>= 1) s += __shfl_down(s, off);
    if (lane == 0) out[b * 16 + c] = s + bias[c];
}

// ---------------------------------------------------------------------------
extern "C" void kernel_launch(void* const* d_in, const int* in_sizes, int n_in,
                              void* d_out, int out_size, void* d_ws, size_t ws_size,
                              hipStream_t stream) {
    const int*   x        = (const int*)d_in[0];
    const int*   seq_lens = (const int*)d_in[1];
    const float* emb      = (const float*)d_in[2];
    const float* cls      = (const float*)d_in[3];
    const float* A        = (const float*)d_in[4];
    const float* A_qkv    = (const float*)d_in[5];
    const float* b        = (const float*)d_in[6];
    const float* W_cls    = (const float*)d_in[7];
    const float* b_cls    = (const float*)d_in[8];
    float* out = (float*)d_out;

    ushort* XbA  = (ushort*)d_ws;
    ushort* XbB  = XbA + (size_t)ROWS * XDIM;
    ushort* Ab   = XbB + (size_t)ROWS * XDIM;
    ushort* Aqb  = Ab + (size_t)PREDIM * 2048;
    float*  pre0 = (float*)(Aqb + (size_t)QKVDIM * 512);
    float*  pre1 = pre0 + (size_t)ROWS * PREDIM;
    ushort* qkvb = (ushort*)pre0;   // overlapped: pre dead after relu_ln

    size_t need2 = (size_t)((char*)(pre1 + (size_t)ROWS * PREDIM) - (char*)d_ws);
    int nsplit = (ws_size >= need2) ? 2 : 1;

    hipMemsetAsync(XbA, 0, (size_t)ROWS * XDIM * sizeof(ushort), stream);
    f2bf_kernel<<<(PREDIM * 2048 + 255) / 256, 256, 0, stream>>>(A, Ab, PREDIM * 2048);
    f2bf_kernel<<<(QKVDIM * 512 + 255) / 256, 256, 0, stream>>>(A_qkv, Aqb, QKVDIM * 512);
    build_u_kernel<<<ROWS, 256, 0, stream>>>(x, emb, cls, XbA, XbB);

    ushort* cur = XbA;
    ushort* nxt = XbB;
    for (int it = 0; it < 12; ++it) {
        // pre = [z | u] @ A^T + b  (split-K=2: 408 blocks, 32 K-steps each)
        gemm_bf16_kernel<<<dim3(17, 12, nsplit), 256, 0, stream>>>(
            cur, XDIM, Ab, b, pre0, nullptr, PREDIM, ROWS, PREDIM,
            2048 / nsplit, 2048, (size_t)ROWS * PREDIM);
        relu_ln_kernel<<<ROWS, 256, 0, stream>>>(
            pre0, nsplit == 2 ? pre1 : nullptr, nxt);
        gemm_bf16_kernel<<<dim3(17, 6, 1), 256, 0, stream>>>(
            nxt + 1024, XDIM, Aqb, nullptr, nullptr, qkvb, QKVDIM, ROWS, QKVDIM,
            512, 512, 0);
        attn_kernel<<<dim3(64, 5), 256, 0, stream>>>(qkvb, seq_lens, nxt);
        ushort* tmp = cur; cur = nxt; nxt = tmp;
    }
    cls_kernel<<<128, 64, 0, stream>>>(cur, W_cls, b_cls, out);
}